// Round 1
// baseline (1170.063 us; speedup 1.0000x reference)
//
#include <hip/hip_runtime.h>

#define S_LEN 2048
#define DMODEL 1024
#define NHEADS 16
#define DKH 64

// ---------------------------------------------------------------------------
// GEMM: C = X @ W^T + bias
//   X: [M][K] row-major, W: [N][K] row-major (nn.Linear weight), bias: [N]
// MODE 0: scatter output to headed layout [B,H,S,DKH]  (B=M/S_LEN, h=n/64, d=n%64)
// MODE 1: flat [M][N]
// Tile 64x64, BK=16, 256 threads, 4x4 register micro-tile per thread.
// ---------------------------------------------------------------------------
template <int MODE>
__global__ __launch_bounds__(256) void gemm_xwt(
    const float* __restrict__ X, const float* __restrict__ W,
    const float* __restrict__ bias, float* __restrict__ C,
    int M, int N, int K)
{
    __shared__ float As[16][64];  // [k][m]
    __shared__ float Bs[16][64];  // [k][n]

    const int t  = threadIdx.x;
    const int tx = t & 15;
    const int ty = t >> 4;
    const int m0 = blockIdx.x << 6;
    const int n0 = blockIdx.y << 6;

    const int lm = t >> 2;         // 0..63 row within tile
    const int lk = (t & 3) << 2;   // 0,4,8,12 k-offset

    const float* xg = X + (size_t)(m0 + lm) * K + lk;
    const float* wg = W + (size_t)(n0 + lm) * K + lk;

    float acc[4][4] = {};

    for (int k0 = 0; k0 < K; k0 += 16) {
        float4 a = *(const float4*)(xg + k0);
        float4 b = *(const float4*)(wg + k0);
        __syncthreads();
        As[lk + 0][lm] = a.x; As[lk + 1][lm] = a.y;
        As[lk + 2][lm] = a.z; As[lk + 3][lm] = a.w;
        Bs[lk + 0][lm] = b.x; Bs[lk + 1][lm] = b.y;
        Bs[lk + 2][lm] = b.z; Bs[lk + 3][lm] = b.w;
        __syncthreads();

        #pragma unroll
        for (int kk = 0; kk < 16; ++kk) {
            float av[4], bv[4];
            *(float4*)av = *(const float4*)&As[kk][ty << 2];
            *(float4*)bv = *(const float4*)&Bs[kk][tx << 2];
            #pragma unroll
            for (int ii = 0; ii < 4; ++ii)
                #pragma unroll
                for (int jj = 0; jj < 4; ++jj)
                    acc[ii][jj] += av[ii] * bv[jj];
        }
    }

    float bv4[4];
    *(float4*)bv4 = *(const float4*)&bias[n0 + (tx << 2)];

    #pragma unroll
    for (int ii = 0; ii < 4; ++ii) {
        const int m = m0 + (ty << 2) + ii;
        const int n = n0 + (tx << 2);
        float4 o;
        o.x = acc[ii][0] + bv4[0];
        o.y = acc[ii][1] + bv4[1];
        o.z = acc[ii][2] + bv4[2];
        o.w = acc[ii][3] + bv4[3];
        if (MODE == 0) {
            const int b = m >> 11;          // m / S_LEN
            const int s = m & (S_LEN - 1);
            const int h = n >> 6;
            const int d = n & 63;
            *(float4*)&C[(((size_t)(b * NHEADS + h) * S_LEN) + s) * DKH + d] = o;
        } else {
            *(float4*)&C[(size_t)m * N + n] = o;
        }
    }
}

// ---------------------------------------------------------------------------
// Flash-style attention with the reference's K/V swap:
//   scores = Q @ V^T / 8,  mask==0 -> -1e9,  softmax,  out = P @ K
// Q/V/K in [B*H][S][64]; out written to attr [B][S][H*64].
// Block: 256 threads, one 64-row Q tile per block; loops 64-wide j tiles.
// ---------------------------------------------------------------------------
__global__ __launch_bounds__(256) void attention_kernel(
    const float* __restrict__ Qh, const float* __restrict__ Vh,
    const float* __restrict__ Kh, const int* __restrict__ mask,
    float* __restrict__ attr)
{
    __shared__ float Qs[64][68];   // [d][i]
    __shared__ float Vs[64][68];   // [d][j]
    __shared__ float Ks[64][68];   // [j][d]
    __shared__ float Ps[64][68];   // [j][i]
    __shared__ float redM[64][17];
    __shared__ float redL[64][17];
    __shared__ float rowM[64];
    __shared__ float rowL[64];

    const int t  = threadIdx.x;
    const int tx = t & 15;
    const int ty = t >> 4;
    const int bh = blockIdx.y;
    const int b  = bh >> 4;
    const int h  = bh & 15;
    const int q0 = blockIdx.x << 6;

    const int lr = t >> 2;         // 0..63
    const int ls = t & 3;

    // Load Q tile transposed into Qs[d][i]
    {
        const float* qbase = Qh + ((size_t)bh * S_LEN + q0 + lr) * DKH;
        #pragma unroll
        for (int r = 0; r < 4; ++r) {
            const int d4 = (ls + (r << 2)) << 2;
            float4 qv = *(const float4*)(qbase + d4);
            Qs[d4 + 0][lr] = qv.x; Qs[d4 + 1][lr] = qv.y;
            Qs[d4 + 2][lr] = qv.z; Qs[d4 + 3][lr] = qv.w;
        }
    }
    if (t < 64) { rowM[t] = -__builtin_inff(); rowL[t] = 0.f; }

    float O[4][4] = {};
    const float* vbase = Vh + (size_t)bh * S_LEN * DKH;
    const float* kbase = Kh + (size_t)bh * S_LEN * DKH;
    const int* mbase = mask + (size_t)b * S_LEN * S_LEN;

    for (int j0 = 0; j0 < S_LEN; j0 += 64) {
        __syncthreads();  // (A) protect Vs/Ks/Ps reuse
        {
            const float* vb = vbase + (size_t)(j0 + lr) * DKH;
            const float* kb = kbase + (size_t)(j0 + lr) * DKH;
            #pragma unroll
            for (int r = 0; r < 4; ++r) {
                const int d4 = (ls + (r << 2)) << 2;
                float4 vv = *(const float4*)(vb + d4);
                Vs[d4 + 0][lr] = vv.x; Vs[d4 + 1][lr] = vv.y;
                Vs[d4 + 2][lr] = vv.z; Vs[d4 + 3][lr] = vv.w;
                float4 kv = *(const float4*)(kb + d4);
                *(float4*)&Ks[lr][d4] = kv;
            }
        }
        __syncthreads();  // (B) staging visible (also first-iter Qs)

        // scores: s[ii][jj], rows i = ty*4+ii, cols j = tx*4+jj
        float s[4][4] = {};
        #pragma unroll 8
        for (int d = 0; d < 64; ++d) {
            float qa[4], va[4];
            *(float4*)qa = *(const float4*)&Qs[d][ty << 2];
            *(float4*)va = *(const float4*)&Vs[d][tx << 2];
            #pragma unroll
            for (int ii = 0; ii < 4; ++ii)
                #pragma unroll
                for (int jj = 0; jj < 4; ++jj)
                    s[ii][jj] += qa[ii] * va[jj];
        }

        // scale + mask
        #pragma unroll
        for (int ii = 0; ii < 4; ++ii) {
            const int gi = q0 + (ty << 2) + ii;
            int4 mv = *(const int4*)(mbase + (size_t)gi * S_LEN + j0 + (tx << 2));
            s[ii][0] = mv.x ? s[ii][0] * 0.125f : -1e9f;
            s[ii][1] = mv.y ? s[ii][1] * 0.125f : -1e9f;
            s[ii][2] = mv.z ? s[ii][2] * 0.125f : -1e9f;
            s[ii][3] = mv.w ? s[ii][3] * 0.125f : -1e9f;
        }

        // local row max
        #pragma unroll
        for (int ii = 0; ii < 4; ++ii) {
            float lm = fmaxf(fmaxf(s[ii][0], s[ii][1]), fmaxf(s[ii][2], s[ii][3]));
            redM[(ty << 2) + ii][tx] = lm;
        }
        __syncthreads();  // (C)

        float alpha[4], mnew[4];
        #pragma unroll
        for (int ii = 0; ii < 4; ++ii) {
            const int i = (ty << 2) + ii;
            float rm = redM[i][0];
            #pragma unroll
            for (int u = 1; u < 16; ++u) rm = fmaxf(rm, redM[i][u]);
            const float mold = rowM[i];
            const float mn = fmaxf(mold, rm);
            mnew[ii] = mn;
            alpha[ii] = (mold == -__builtin_inff()) ? 0.f : __expf(mold - mn);
        }

        #pragma unroll
        for (int ii = 0; ii < 4; ++ii) {
            const int i = (ty << 2) + ii;
            const float p0 = __expf(s[ii][0] - mnew[ii]);
            const float p1 = __expf(s[ii][1] - mnew[ii]);
            const float p2 = __expf(s[ii][2] - mnew[ii]);
            const float p3 = __expf(s[ii][3] - mnew[ii]);
            redL[i][tx] = (p0 + p1) + (p2 + p3);
            Ps[(tx << 2) + 0][i] = p0;
            Ps[(tx << 2) + 1][i] = p1;
            Ps[(tx << 2) + 2][i] = p2;
            Ps[(tx << 2) + 3][i] = p3;
            O[ii][0] *= alpha[ii]; O[ii][1] *= alpha[ii];
            O[ii][2] *= alpha[ii]; O[ii][3] *= alpha[ii];
        }
        __syncthreads();  // (D)

        if (tx == 0) {
            #pragma unroll
            for (int ii = 0; ii < 4; ++ii) {
                const int i = (ty << 2) + ii;
                float rs = 0.f;
                #pragma unroll
                for (int u = 0; u < 16; ++u) rs += redL[i][u];
                rowL[i] = rowL[i] * alpha[ii] + rs;
                rowM[i] = mnew[ii];
            }
        }

        // O += P @ K
        #pragma unroll 8
        for (int j = 0; j < 64; ++j) {
            float pa[4], ka[4];
            *(float4*)pa = *(const float4*)&Ps[j][ty << 2];
            *(float4*)ka = *(const float4*)&Ks[j][tx << 2];
            #pragma unroll
            for (int ii = 0; ii < 4; ++ii)
                #pragma unroll
                for (int jj = 0; jj < 4; ++jj)
                    O[ii][jj] += pa[ii] * ka[jj];
        }
    }
    __syncthreads();

    #pragma unroll
    for (int ii = 0; ii < 4; ++ii) {
        const int i = (ty << 2) + ii;
        const float inv = 1.f / rowL[i];
        float4 o;
        o.x = O[ii][0] * inv; o.y = O[ii][1] * inv;
        o.z = O[ii][2] * inv; o.w = O[ii][3] * inv;
        *(float4*)&attr[((size_t)(b * S_LEN) + q0 + i) * DMODEL + (h << 6) + (tx << 2)] = o;
    }
}

// ---------------------------------------------------------------------------
extern "C" void kernel_launch(void* const* d_in, const int* in_sizes, int n_in,
                              void* d_out, int out_size, void* d_ws, size_t ws_size,
                              hipStream_t stream) {
    const float* value = (const float*)d_in[0];
    const float* key   = (const float*)d_in[1];
    const float* query = (const float*)d_in[2];
    const int*   mask  = (const int*)d_in[3];
    const float* Wv = (const float*)d_in[4];
    const float* bv = (const float*)d_in[5];
    const float* Wk = (const float*)d_in[6];
    const float* bk = (const float*)d_in[7];
    const float* Wq = (const float*)d_in[8];
    const float* bq = (const float*)d_in[9];
    const float* Wo = (const float*)d_in[10];
    const float* bo = (const float*)d_in[11];
    float* out = (float*)d_out;

    const int B = 2, M = B * S_LEN;                 // 4096
    const size_t bufElems = (size_t)M * DMODEL;     // 4,194,304

    float* ws = (float*)d_ws;
    float* q    = ws;
    float* k    = ws + bufElems;
    float* v    = ws + 2 * bufElems;
    float* attr = ws + 3 * bufElems;

    dim3 gemmGrid(M / 64, DMODEL / 64);   // 64 x 16
    dim3 blk(256);

    gemm_xwt<0><<<gemmGrid, blk, 0, stream>>>(query, Wq, bq, q, M, DMODEL, DMODEL);
    gemm_xwt<0><<<gemmGrid, blk, 0, stream>>>(key,   Wk, bk, k, M, DMODEL, DMODEL);
    gemm_xwt<0><<<gemmGrid, blk, 0, stream>>>(value, Wv, bv, v, M, DMODEL, DMODEL);

    dim3 attnGrid(S_LEN / 64, B * NHEADS);  // 32 x 32
    attention_kernel<<<attnGrid, blk, 0, stream>>>(q, v, k, mask, attr);

    gemm_xwt<1><<<gemmGrid, blk, 0, stream>>>(attr, Wo, bo, out, M, DMODEL, DMODEL);
}

// Round 2
// 400.789 us; speedup vs baseline: 2.9194x; 2.9194x over previous
//
#include <hip/hip_runtime.h>

#define S_LEN 2048
#define DMODEL 1024
#define NHEADS 16
#define DKH 64

typedef __attribute__((ext_vector_type(8))) short bf16x8;
typedef __attribute__((ext_vector_type(4))) float f32x4;

static __device__ __forceinline__ short f2bf(float f) {
    unsigned b = __float_as_uint(f);
    b = (b + 0x7FFFu + ((b >> 16) & 1u)) >> 16;   // RNE
    return (short)b;
}

static __device__ __forceinline__ f32x4 mfma16(bf16x8 a, bf16x8 b, f32x4 c) {
    return __builtin_amdgcn_mfma_f32_16x16x32_bf16(a, b, c, 0, 0, 0);
}

struct GemmBatch {
    const void* X[3];
    const float* W[3];
    const float* Bv[3];
    void* C[3];
};

// ---------------------------------------------------------------------------
// C = X @ W^T + bias, MFMA bf16. X: [4096][1024] fp32 (or bf16 if ABF16),
// W: [1024][1024] fp32. MODE 0: bf16 headed out [B][H][S][DKH]; MODE 1: fp32
// flat. Tile 128x128, BK=32, 256 threads = 4 waves, each wave 64x64 (4x4
// 16x16x32 tiles). fp32->bf16 conversion fused into LDS staging.
// ---------------------------------------------------------------------------
template <int MODE, bool ABF16>
__global__ __launch_bounds__(256) void gemm_mfma(GemmBatch args)
{
    constexpr int K = DMODEL, N = DMODEL;
    constexpr int PITCH = 40;                  // bf16 pitch; 80B, 16B-aligned
    __shared__ short Ah[128 * PITCH];
    __shared__ short Bh[128 * PITCH];

    const int z = blockIdx.z;
    const float* Wg = args.W[z];
    const float* bias = args.Bv[z];

    const int t = threadIdx.x;
    const int m0 = blockIdx.x << 7;
    const int n0 = blockIdx.y << 7;

    const int wid = t >> 6;
    const int lane = t & 63;
    const int l15 = lane & 15;
    const int lq = lane >> 4;
    const int wm = (wid >> 1) << 6;
    const int wn = (wid & 1) << 6;

    const int srow = t >> 1;                   // 0..127
    const int shalf = (t & 1) << 4;            // 0 / 16

    const float* wrow = Wg + (size_t)(n0 + srow) * K + shalf;

    f32x4 acc[4][4] = {};

    for (int k0 = 0; k0 < K; k0 += 32) {
        short a16[16], b16[16];
        if (ABF16) {
            const short* xg = (const short*)args.X[z] + (size_t)(m0 + srow) * K + shalf + k0;
            *(uint4*)(a16 + 0) = *(const uint4*)(xg + 0);
            *(uint4*)(a16 + 8) = *(const uint4*)(xg + 8);
        } else {
            const float* xg = (const float*)args.X[z] + (size_t)(m0 + srow) * K + shalf + k0;
            float xv[16];
            #pragma unroll
            for (int r = 0; r < 4; ++r)
                *(float4*)(xv + 4 * r) = *(const float4*)(xg + 4 * r);
            #pragma unroll
            for (int e = 0; e < 16; ++e) a16[e] = f2bf(xv[e]);
        }
        {
            float wv[16];
            #pragma unroll
            for (int r = 0; r < 4; ++r)
                *(float4*)(wv + 4 * r) = *(const float4*)(wrow + k0 + 4 * r);
            #pragma unroll
            for (int e = 0; e < 16; ++e) b16[e] = f2bf(wv[e]);
        }
        __syncthreads();
        *(uint4*)&Ah[srow * PITCH + shalf + 0] = *(uint4*)(a16 + 0);
        *(uint4*)&Ah[srow * PITCH + shalf + 8] = *(uint4*)(a16 + 8);
        *(uint4*)&Bh[srow * PITCH + shalf + 0] = *(uint4*)(b16 + 0);
        *(uint4*)&Bh[srow * PITCH + shalf + 8] = *(uint4*)(b16 + 8);
        __syncthreads();

        bf16x8 af[4], bf[4];
        #pragma unroll
        for (int i = 0; i < 4; ++i)
            af[i] = *(const bf16x8*)&Ah[(wm + i * 16 + l15) * PITCH + lq * 8];
        #pragma unroll
        for (int j = 0; j < 4; ++j)
            bf[j] = *(const bf16x8*)&Bh[(wn + j * 16 + l15) * PITCH + lq * 8];
        #pragma unroll
        for (int i = 0; i < 4; ++i)
            #pragma unroll
            for (int j = 0; j < 4; ++j)
                acc[i][j] = mfma16(af[i], bf[j], acc[i][j]);
    }

    // epilogue: D row = lq*4+r, col = l15 within each 16x16 tile
    #pragma unroll
    for (int j = 0; j < 4; ++j) {
        const int n = n0 + wn + j * 16 + l15;
        const float bn = bias[n];
        #pragma unroll
        for (int i = 0; i < 4; ++i) {
            #pragma unroll
            for (int r = 0; r < 4; ++r) {
                const int m = m0 + wm + i * 16 + lq * 4 + r;
                const float val = acc[i][j][r] + bn;
                if (MODE == 0) {
                    const int b = m >> 11, s = m & (S_LEN - 1);
                    const int h = n >> 6, d = n & 63;
                    ((short*)args.C[z])[(((size_t)(b * NHEADS + h) * S_LEN) + s) * DKH + d] = f2bf(val);
                } else {
                    ((float*)args.C[z])[(size_t)m * N + n] = val;
                }
            }
        }
    }
}

// ---------------------------------------------------------------------------
// Flash attention with reference's K/V swap: scores = Q@V^T/8 (mask==0 ->
// -1e9), out = softmax @ K. All operands bf16 headed [BH][S][64]; out attr
// bf16 flat [B*S][1024]. Block = 4 waves, 64 Q rows (16/wave); j-chunks of 64.
// Q frags from global; V staged in LDS; K transposed into LDS; P via LDS.
// ---------------------------------------------------------------------------
__global__ __launch_bounds__(256) void attn_mfma(
    const short* __restrict__ Qh, const short* __restrict__ Vh,
    const short* __restrict__ Kh, const int* __restrict__ mask,
    short* __restrict__ attr)
{
    constexpr int VP = 72;                      // bf16 pitch; 144B, 16B-aligned
    __shared__ short Vs[64 * VP];               // [j][dk]
    __shared__ short Kt[64 * VP];               // [dk][j] (transposed K)
    __shared__ short Ps[64 * VP];               // [i][j], per-wave 16-row bands

    const int t = threadIdx.x;
    const int wid = t >> 6;
    const int lane = t & 63;
    const int l15 = lane & 15;
    const int lq = lane >> 4;
    const int bh = blockIdx.y, b = bh >> 4, h = bh & 15;
    const int q0 = blockIdx.x << 6;

    // Q frags (A operand): lane holds Q[row=l15][k=lq*8+e], 2 k-steps
    bf16x8 qf[2];
    {
        const short* qp = Qh + ((size_t)bh * S_LEN + q0 + wid * 16 + l15) * DKH + lq * 8;
        qf[0] = *(const bf16x8*)(qp);
        qf[1] = *(const bf16x8*)(qp + 32);
    }

    const int vrow = t >> 2, vcb = (t & 3) << 4;   // V staging: 4 thr/row
    const int kj = t & 63, kdb = (t >> 6) << 4;    // K staging: 1 row/thr, 16 d

    const short* vg = Vh + (size_t)bh * S_LEN * DKH;
    const short* kg = Kh + (size_t)bh * S_LEN * DKH;
    const int* mb = mask + (size_t)b * S_LEN * S_LEN
                  + (size_t)(q0 + wid * 16 + lq * 4) * S_LEN;

    float m_i[4], l_i[4];
    #pragma unroll
    for (int r = 0; r < 4; ++r) { m_i[r] = -1e9f; l_i[r] = 0.f; }
    f32x4 O[4] = {};

    for (int j0 = 0; j0 < S_LEN; j0 += 64) {
        __syncthreads();   // prior iteration's frag reads done
        {   // stage V tile [64][64]
            const short* p = vg + (size_t)(j0 + vrow) * DKH + vcb;
            uint4 v0 = *(const uint4*)(p);
            uint4 v1 = *(const uint4*)(p + 8);
            *(uint4*)&Vs[vrow * VP + vcb + 0] = v0;
            *(uint4*)&Vs[vrow * VP + vcb + 8] = v1;
        }
        {   // stage K tile transposed -> Kt[d][j]
            const short* p = kg + (size_t)(j0 + kj) * DKH + kdb;
            short kv[16];
            *(uint4*)(kv + 0) = *(const uint4*)(p + 0);
            *(uint4*)(kv + 8) = *(const uint4*)(p + 8);
            #pragma unroll
            for (int e = 0; e < 16; ++e)
                Kt[(kdb + e) * VP + kj] = kv[e];
        }
        __syncthreads();

        // scores S = Q @ V^T : B-frag lane holds V[n=l15][k=lq*8+e]
        f32x4 sc[4];
        #pragma unroll
        for (int nt = 0; nt < 4; ++nt) {
            bf16x8 v0 = *(const bf16x8*)&Vs[(nt * 16 + l15) * VP + lq * 8];
            bf16x8 v1 = *(const bf16x8*)&Vs[(nt * 16 + l15) * VP + 32 + lq * 8];
            f32x4 c = {};
            c = mfma16(qf[0], v0, c);
            c = mfma16(qf[1], v1, c);
            sc[nt] = c;
        }

        // scale + mask (row i = lq*4+r, col j = nt*16+l15)
        #pragma unroll
        for (int nt = 0; nt < 4; ++nt)
            #pragma unroll
            for (int r = 0; r < 4; ++r) {
                const int mv = mb[(size_t)r * S_LEN + j0 + nt * 16 + l15];
                sc[nt][r] = mv ? sc[nt][r] * 0.125f : -1e9f;
            }

        // row max across 4 tiles + 16 lanes
        float rmx[4];
        #pragma unroll
        for (int r = 0; r < 4; ++r)
            rmx[r] = fmaxf(fmaxf(sc[0][r], sc[1][r]), fmaxf(sc[2][r], sc[3][r]));
        #pragma unroll
        for (int d = 1; d < 16; d <<= 1)
            #pragma unroll
            for (int r = 0; r < 4; ++r)
                rmx[r] = fmaxf(rmx[r], __shfl_xor(rmx[r], d, 64));

        float alpha[4], rsum[4];
        #pragma unroll
        for (int r = 0; r < 4; ++r) {
            const float mn = fmaxf(m_i[r], rmx[r]);
            alpha[r] = __expf(m_i[r] - mn);
            m_i[r] = mn;
            rsum[r] = 0.f;
        }

        // p = exp(s - m), store bf16 to Ps, accumulate row sums
        #pragma unroll
        for (int nt = 0; nt < 4; ++nt)
            #pragma unroll
            for (int r = 0; r < 4; ++r) {
                const float p = __expf(sc[nt][r] - m_i[r]);
                rsum[r] += p;
                Ps[(wid * 16 + lq * 4 + r) * VP + nt * 16 + l15] = f2bf(p);
            }
        #pragma unroll
        for (int d = 1; d < 16; d <<= 1)
            #pragma unroll
            for (int r = 0; r < 4; ++r)
                rsum[r] += __shfl_xor(rsum[r], d, 64);
        #pragma unroll
        for (int r = 0; r < 4; ++r)
            l_i[r] = l_i[r] * alpha[r] + rsum[r];

        #pragma unroll
        for (int nt = 0; nt < 4; ++nt)
            #pragma unroll
            for (int r = 0; r < 4; ++r)
                O[nt][r] *= alpha[r];

        // O += P @ K  (P A-frag from Ps, same-wave dependency; K B-frag from Kt)
        bf16x8 pf0 = *(const bf16x8*)&Ps[(wid * 16 + l15) * VP + lq * 8];
        bf16x8 pf1 = *(const bf16x8*)&Ps[(wid * 16 + l15) * VP + 32 + lq * 8];
        #pragma unroll
        for (int nt = 0; nt < 4; ++nt) {
            bf16x8 k0f = *(const bf16x8*)&Kt[(nt * 16 + l15) * VP + lq * 8];
            bf16x8 k1f = *(const bf16x8*)&Kt[(nt * 16 + l15) * VP + 32 + lq * 8];
            O[nt] = mfma16(pf0, k0f, O[nt]);
            O[nt] = mfma16(pf1, k1f, O[nt]);
        }
    }

    // epilogue: attr[b][s][h*64 + d] bf16
    #pragma unroll
    for (int r = 0; r < 4; ++r) {
        const float inv = 1.f / l_i[r];
        const size_t row = (size_t)b * S_LEN + q0 + wid * 16 + lq * 4 + r;
        #pragma unroll
        for (int nt = 0; nt < 4; ++nt)
            attr[row * DMODEL + h * 64 + nt * 16 + l15] = f2bf(O[nt][r] * inv);
    }
}

// ---------------------------------------------------------------------------
extern "C" void kernel_launch(void* const* d_in, const int* in_sizes, int n_in,
                              void* d_out, int out_size, void* d_ws, size_t ws_size,
                              hipStream_t stream) {
    const float* value = (const float*)d_in[0];
    const float* key   = (const float*)d_in[1];
    const float* query = (const float*)d_in[2];
    const int*   mask  = (const int*)d_in[3];
    const float* Wv = (const float*)d_in[4];
    const float* bv = (const float*)d_in[5];
    const float* Wk = (const float*)d_in[6];
    const float* bk = (const float*)d_in[7];
    const float* Wq = (const float*)d_in[8];
    const float* bq = (const float*)d_in[9];
    const float* Wo = (const float*)d_in[10];
    const float* bo = (const float*)d_in[11];
    float* out = (float*)d_out;

    const size_t bufElems = (size_t)4096 * DMODEL;   // 4.19M bf16 elems each
    short* q    = (short*)d_ws;
    short* k    = q + bufElems;
    short* v    = k + bufElems;
    short* attr = v + bufElems;

    GemmBatch g1;
    g1.X[0] = query; g1.W[0] = Wq; g1.Bv[0] = bq; g1.C[0] = q;
    g1.X[1] = key;   g1.W[1] = Wk; g1.Bv[1] = bk; g1.C[1] = k;
    g1.X[2] = value; g1.W[2] = Wv; g1.Bv[2] = bv; g1.C[2] = v;
    gemm_mfma<0, false><<<dim3(32, 8, 3), 256, 0, stream>>>(g1);

    attn_mfma<<<dim3(S_LEN / 64, 2 * NHEADS), 256, 0, stream>>>(q, v, k, mask, attr);

    GemmBatch g2;
    g2.X[0] = attr; g2.W[0] = Wo; g2.Bv[0] = bo; g2.C[0] = out;
    g2.X[1] = attr; g2.W[1] = Wo; g2.Bv[1] = bo; g2.C[1] = out;
    g2.X[2] = attr; g2.W[2] = Wo; g2.Bv[2] = bo; g2.C[2] = out;
    gemm_mfma<1, true><<<dim3(32, 8, 1), 256, 0, stream>>>(g2);
}

// Round 3
// 315.319 us; speedup vs baseline: 3.7107x; 1.2711x over previous
//
#include <hip/hip_runtime.h>

#define S_LEN 2048
#define DMODEL 1024
#define NHEADS 16
#define DKH 64

typedef __attribute__((ext_vector_type(8))) short bf16x8;
typedef __attribute__((ext_vector_type(4))) float f32x4;

static __device__ __forceinline__ short f2bf(float f) {
    unsigned b = __float_as_uint(f);
    b = (b + 0x7FFFu + ((b >> 16) & 1u)) >> 16;   // RNE
    return (short)b;
}

static __device__ __forceinline__ f32x4 mfma16(bf16x8 a, bf16x8 b, f32x4 c) {
    return __builtin_amdgcn_mfma_f32_16x16x32_bf16(a, b, c, 0, 0, 0);
}

// async global->LDS, 16B per lane; dest = ldsbase + lane*16
static __device__ __forceinline__ void glds16(const short* g, short* l) {
    __builtin_amdgcn_global_load_lds(
        (const __attribute__((address_space(1))) void*)g,
        (__attribute__((address_space(3))) void*)l, 16, 0, 0);
}

// ---------------------------------------------------------------------------
// fp32 -> bf16 conversion: segments {query,key,value: 4M each}{Wq,Wk,Wv,Wo: 1M}
// ---------------------------------------------------------------------------
struct CvtArgs { const float* src[7]; short* dst[7]; };

__global__ __launch_bounds__(256) void cvt_bf16(CvtArgs a) {
    const size_t i8 = ((size_t)blockIdx.x * 256 + threadIdx.x) * 8;
    int seg; size_t off;
    if (i8 < ((size_t)12 << 20)) { seg = (int)(i8 >> 22); off = i8 & ((1u << 22) - 1); }
    else { size_t r = i8 - ((size_t)12 << 20); seg = 3 + (int)(r >> 20); off = r & ((1u << 20) - 1); }
    const float* s = a.src[seg] + off;
    float4 x0 = *(const float4*)s, x1 = *(const float4*)(s + 4);
    short o[8];
    o[0] = f2bf(x0.x); o[1] = f2bf(x0.y); o[2] = f2bf(x0.z); o[3] = f2bf(x0.w);
    o[4] = f2bf(x1.x); o[5] = f2bf(x1.y); o[6] = f2bf(x1.z); o[7] = f2bf(x1.w);
    *(uint4*)(a.dst[seg] + off) = *(uint4*)o;
}

// ---------------------------------------------------------------------------
// mask [B][1][S][S] int32 -> bit-packed uint64 words, bit i = col (w*64+i)
// ---------------------------------------------------------------------------
__global__ __launch_bounds__(256) void pack_mask(const int* __restrict__ mask,
                                                 unsigned long long* __restrict__ mw) {
    const int wave = (blockIdx.x << 2) + (threadIdx.x >> 6);  // 0..2047
    const int lane = threadIdx.x & 63;
    const size_t base = (size_t)wave * 64;
    for (int it = 0; it < 64; ++it) {
        const size_t w = base + it;
        const int m = mask[(w << 6) + lane];
        unsigned long long bal = __ballot(m != 0);
        if (lane == 0) mw[w] = bal;
    }
}

// ---------------------------------------------------------------------------
// C = X @ W^T + bias, all-bf16 inputs, m97-style: 128x128 tile, BK=32,
// global_load_lds(16B), XOR-swizzled k-blocks (conflict-free frag reads).
// MODE 0: bf16 headed out [B][H][S][DKH]; MODE 1: fp32 flat [M][N].
// ---------------------------------------------------------------------------
struct GemmArgs { const short* X[3]; const short* W[3]; const float* B[3]; void* C[3]; };

template <int MODE>
__global__ __launch_bounds__(256) void gemm_bt(GemmArgs a) {
    __shared__ short Ah[128 * 32];
    __shared__ short Bh[128 * 32];
    const int z = blockIdx.z;
    const short* X = a.X[z];
    const short* W = a.W[z];
    const float* bias = a.B[z];

    const int t = threadIdx.x, wid = t >> 6, lane = t & 63;
    const int l15 = lane & 15, lq = lane >> 4;
    const int m0 = blockIdx.x << 7, n0 = blockIdx.y << 7;
    const int wm = (wid >> 1) << 6, wn = (wid & 1) << 6;

    // staging: lane fetches row r0+(lane>>2), k-block (lane&3)^((lane>>3)&3)
    const int kb = (lane & 3) ^ ((lane >> 3) & 3);
    const int r0 = (wid << 5) + (lane >> 2);
    const short* ag0 = X + (size_t)(m0 + r0) * 1024 + (kb << 3);
    const short* ag1 = ag0 + 16 * 1024;
    const short* bg0 = W + (size_t)(n0 + r0) * 1024 + (kb << 3);
    const short* bg1 = bg0 + 16 * 1024;
    short* lA0 = Ah + (wid << 5) * 32;
    short* lA1 = lA0 + 16 * 32;
    short* lB0 = Bh + (wid << 5) * 32;
    short* lB1 = lB0 + 16 * 32;

    const int fpos = (lq ^ ((l15 >> 1) & 3)) << 3;   // lane-constant frag k-offset

    f32x4 acc[4][4] = {};

    for (int k0 = 0; k0 < 1024; k0 += 32) {
        __syncthreads();
        glds16(ag0, lA0); glds16(ag1, lA1);
        glds16(bg0, lB0); glds16(bg1, lB1);
        ag0 += 32; ag1 += 32; bg0 += 32; bg1 += 32;
        __syncthreads();

        bf16x8 af[4], bfr[4];
        #pragma unroll
        for (int i = 0; i < 4; ++i)
            af[i] = *(const bf16x8*)&Ah[(wm + i * 16 + l15) * 32 + fpos];
        #pragma unroll
        for (int j = 0; j < 4; ++j)
            bfr[j] = *(const bf16x8*)&Bh[(wn + j * 16 + l15) * 32 + fpos];
        #pragma unroll
        for (int i = 0; i < 4; ++i)
            #pragma unroll
            for (int j = 0; j < 4; ++j)
                acc[i][j] = mfma16(af[i], bfr[j], acc[i][j]);
    }

    #pragma unroll
    for (int j = 0; j < 4; ++j) {
        const int n = n0 + wn + j * 16 + l15;
        const float bn = bias[n];
        #pragma unroll
        for (int i = 0; i < 4; ++i) {
            const int mbase = m0 + wm + i * 16 + (lq << 2);
            #pragma unroll
            for (int r = 0; r < 4; ++r) {
                const float val = acc[i][j][r] + bn;
                const int m = mbase + r;
                if (MODE == 0) {
                    const int b = m >> 11, s = m & 2047, h = n >> 6, d = n & 63;
                    ((short*)a.C[z])[((((size_t)(b * 16 + h)) << 11) + s) * 64 + d] = f2bf(val);
                } else {
                    ((float*)a.C[z])[((size_t)m << 10) + n] = val;
                }
            }
        }
    }
}

// ---------------------------------------------------------------------------
// Flash attention (reference K/V swap): S = Q@V^T/8, mask, softmax, O = P@K.
// Fixed-max softmax (no running max/alpha), deferred l-reduction, truncated
// bf16 P with l summed from the same truncated values (bias cancels in O/l).
// Ps and Kt use identical column permutation phi(j)=(j&15)*4+(j>>4) so the
// MFMA k-sum is invariant; Ps writes become packed ushort4.
// 128 q-rows/block (4 waves x 32 rows), j-chunks of 64.
// ---------------------------------------------------------------------------
__global__ __launch_bounds__(256) void attn_mfma(
    const short* __restrict__ Qh, const short* __restrict__ Vh,
    const short* __restrict__ Kh, const unsigned long long* __restrict__ MW,
    short* __restrict__ attr)
{
    constexpr int VP = 72;
    __shared__ short Vs[64 * VP];    // [j][d]
    __shared__ short Kt[64 * VP];    // [d][phi(j)]
    __shared__ short Ps[128 * VP];   // [qrow][phi(j)]

    const int t = threadIdx.x, wid = t >> 6, lane = t & 63;
    const int l15 = lane & 15, lq = lane >> 4;
    const int bh = blockIdx.y, b = bh >> 4, h = bh & 15;
    const int q0 = blockIdx.x << 7;

    bf16x8 qf[2][2];
    #pragma unroll
    for (int mt = 0; mt < 2; ++mt) {
        const short* qp = Qh + ((size_t)bh * 2048 + q0 + (wid << 5) + mt * 16 + l15) * 64 + (lq << 3);
        qf[mt][0] = *(const bf16x8*)qp;
        qf[mt][1] = *(const bf16x8*)(qp + 32);
    }

    const int vrow = t >> 2, vcb = (t & 3) << 4;
    const int kj = lane, kdb = wid << 4;
    const int kphi = ((kj & 15) << 2) + (kj >> 4);

    const short* vg = Vh + (size_t)bh * 2048 * 64;
    const short* kg = Kh + (size_t)bh * 2048 * 64;
    const unsigned long long* mwp = MW + ((size_t)b * 2048 + q0 + (wid << 5) + (lq << 2)) * 32;

    float rsum[2][4] = {};
    f32x4 O[2][4] = {};

    for (int jc = 0; jc < 32; ++jc) {
        const int j0 = jc << 6;
        __syncthreads();
        {   // stage V [j][d]
            const short* p = vg + (size_t)(j0 + vrow) * 64 + vcb;
            *(uint4*)&Vs[vrow * VP + vcb + 0] = *(const uint4*)p;
            *(uint4*)&Vs[vrow * VP + vcb + 8] = *(const uint4*)(p + 8);
        }
        {   // stage K transposed+permuted -> Kt[d][phi(j)]
            const short* p = kg + (size_t)(j0 + kj) * 64 + kdb;
            short kv[16];
            *(uint4*)(kv + 0) = *(const uint4*)(p + 0);
            *(uint4*)(kv + 8) = *(const uint4*)(p + 8);
            #pragma unroll
            for (int e = 0; e < 16; ++e)
                Kt[(kdb + e) * VP + kphi] = kv[e];
        }
        // mask words for this lane's 8 rows (issue early, used after MFMA)
        uint2 mwv[2][4];
        #pragma unroll
        for (int mt = 0; mt < 2; ++mt)
            #pragma unroll
            for (int r = 0; r < 4; ++r)
                mwv[mt][r] = *(const uint2*)&mwp[(size_t)(mt * 16 + r) * 32 + jc];
        __syncthreads();

        // V frags shared across both m-tiles
        bf16x8 vf[4][2];
        #pragma unroll
        for (int nt = 0; nt < 4; ++nt) {
            vf[nt][0] = *(const bf16x8*)&Vs[(nt * 16 + l15) * VP + (lq << 3)];
            vf[nt][1] = *(const bf16x8*)&Vs[(nt * 16 + l15) * VP + 32 + (lq << 3)];
        }

        #pragma unroll
        for (int mt = 0; mt < 2; ++mt) {
            f32x4 sc[4];
            #pragma unroll
            for (int nt = 0; nt < 4; ++nt) {
                f32x4 c = {};
                c = mfma16(qf[mt][0], vf[nt][0], c);
                c = mfma16(qf[mt][1], vf[nt][1], c);
                sc[nt] = c;
            }
            #pragma unroll
            for (int r = 0; r < 4; ++r) {
                ushort4 pb;
                #pragma unroll
                for (int nt = 0; nt < 4; ++nt) {
                    const unsigned sel = (nt < 2) ? mwv[mt][r].x : mwv[mt][r].y;
                    const unsigned bit = (sel >> ((nt & 1) * 16 + l15)) & 1u;
                    float p = __expf(sc[nt][r] * 0.125f);
                    p = bit ? p : 0.f;
                    const unsigned u = __float_as_uint(p) & 0xFFFF0000u;  // truncate
                    rsum[mt][r] += __uint_as_float(u);                    // l matches stored P
                    ((unsigned short*)&pb)[nt] = (unsigned short)(u >> 16);
                }
                // packed write: physical cols l15*4 + nt  (phi permutation)
                *(ushort4*)&Ps[((wid << 5) + mt * 16 + (lq << 2) + r) * VP + (l15 << 2)] = pb;
            }
        }

        // O += P @ K (wave-private Ps band; Kt shared, behind barrier)
        bf16x8 pf[2][2];
        #pragma unroll
        for (int mt = 0; mt < 2; ++mt) {
            const short* pp = &Ps[((wid << 5) + mt * 16 + l15) * VP];
            pf[mt][0] = *(const bf16x8*)(pp + (lq << 3));
            pf[mt][1] = *(const bf16x8*)(pp + 32 + (lq << 3));
        }
        #pragma unroll
        for (int nt = 0; nt < 4; ++nt) {
            const short* kp = &Kt[(nt * 16 + l15) * VP];
            bf16x8 kf0 = *(const bf16x8*)(kp + (lq << 3));
            bf16x8 kf1 = *(const bf16x8*)(kp + 32 + (lq << 3));
            #pragma unroll
            for (int mt = 0; mt < 2; ++mt) {
                O[mt][nt] = mfma16(pf[mt][0], kf0, O[mt][nt]);
                O[mt][nt] = mfma16(pf[mt][1], kf1, O[mt][nt]);
            }
        }
    }

    // deferred l reduction over the 16-lane groups
    #pragma unroll
    for (int mt = 0; mt < 2; ++mt)
        #pragma unroll
        for (int r = 0; r < 4; ++r) {
            float s = rsum[mt][r];
            #pragma unroll
            for (int d = 1; d < 16; d <<= 1)
                s += __shfl_xor(s, d, 64);
            rsum[mt][r] = s;
        }

    #pragma unroll
    for (int mt = 0; mt < 2; ++mt)
        #pragma unroll
        for (int r = 0; r < 4; ++r) {
            const float inv = 1.f / rsum[mt][r];
            const size_t row = (size_t)b * 2048 + q0 + (wid << 5) + mt * 16 + (lq << 2) + r;
            #pragma unroll
            for (int nt = 0; nt < 4; ++nt)
                attr[row * 1024 + (h << 6) + nt * 16 + l15] = f2bf(O[mt][nt][r] * inv);
        }
}

// ---------------------------------------------------------------------------
extern "C" void kernel_launch(void* const* d_in, const int* in_sizes, int n_in,
                              void* d_out, int out_size, void* d_ws, size_t ws_size,
                              hipStream_t stream) {
    const float* value = (const float*)d_in[0];
    const float* key   = (const float*)d_in[1];
    const float* query = (const float*)d_in[2];
    const int*   mask  = (const int*)d_in[3];
    const float* bv = (const float*)d_in[5];
    const float* bk = (const float*)d_in[7];
    const float* bq = (const float*)d_in[9];
    const float* bo = (const float*)d_in[11];
    float* out = (float*)d_out;

    const size_t M1 = (size_t)1 << 20, M4 = (size_t)1 << 22;
    short* ws = (short*)d_ws;
    // layout (shorts): Xq@0(=attr later) Xk@4M Xv@8M Wc@12M(4x1M) qh@16M kh@20M vh@24M maskw@28M
    short* Xq = ws;
    short* Xk = ws + M4;
    short* Xv = ws + 2 * M4;
    short* Wc0 = ws + 3 * M4;
    short* Wc1 = Wc0 + M1;
    short* Wc2 = Wc1 + M1;
    short* Wc3 = Wc2 + M1;
    short* qh = ws + 4 * M4;
    short* kh = ws + 5 * M4;
    short* vh = ws + 6 * M4;
    unsigned long long* maskw = (unsigned long long*)(ws + 7 * M4);
    short* attr = Xq;   // Xq dead after proj GEMM

    CvtArgs cv;
    cv.src[0] = query; cv.dst[0] = Xq;
    cv.src[1] = key;   cv.dst[1] = Xk;
    cv.src[2] = value; cv.dst[2] = Xv;
    cv.src[3] = (const float*)d_in[8];  cv.dst[3] = Wc0;  // Wq
    cv.src[4] = (const float*)d_in[6];  cv.dst[4] = Wc1;  // Wk
    cv.src[5] = (const float*)d_in[4];  cv.dst[5] = Wc2;  // Wv
    cv.src[6] = (const float*)d_in[10]; cv.dst[6] = Wc3;  // Wo
    cvt_bf16<<<8192, 256, 0, stream>>>(cv);

    pack_mask<<<512, 256, 0, stream>>>(mask, maskw);

    GemmArgs g1;
    g1.X[0] = Xq; g1.W[0] = Wc0; g1.B[0] = bq; g1.C[0] = qh;
    g1.X[1] = Xk; g1.W[1] = Wc1; g1.B[1] = bk; g1.C[1] = kh;
    g1.X[2] = Xv; g1.W[2] = Wc2; g1.B[2] = bv; g1.C[2] = vh;
    gemm_bt<0><<<dim3(32, 8, 3), 256, 0, stream>>>(g1);

    attn_mfma<<<dim3(16, 32), 256, 0, stream>>>(qh, vh, kh, maskw, attr);

    GemmArgs g2;
    g2.X[0] = attr; g2.W[0] = Wc3; g2.B[0] = bo; g2.C[0] = out;
    g2.X[1] = attr; g2.W[1] = Wc3; g2.B[1] = bo; g2.C[1] = out;
    g2.X[2] = attr; g2.W[2] = Wc3; g2.B[2] = bo; g2.C[2] = out;
    gemm_bt<1><<<dim3(32, 8, 1), 256, 0, stream>>>(g2);
}